// Round 1
// baseline (246.689 us; speedup 1.0000x reference)
//
#include <hip/hip_runtime.h>

// Problem: out = sum(left @ weight) + bias
//   left:   (8192, 4096) f32
//   weight: (4096, 4096) f32
//   bias:   (1,) f32
// Factorization: sum(L@W) = dot(colsum(L), rowsum(W)).

#define DIM 4096          // DIM1 == DIM2 == 4096
#define M_ROWS 8192

constexpr int CHUNKS = 128;          // row chunks of left
constexpr int CHUNK_ROWS = 64;       // 128 * 64 = 8192
constexpr int LEFT_BLOCKS = 512;     // CHUNKS * 4 col-blocks (1024 cols each, via float4)
constexpr int ROWS_PER_WBLOCK = 8;   // weight rows per block
constexpr int WEIGHT_BLOCKS = 512;   // 512 * 8 = 4096 rows

// Fused: left column-sum partials (no atomics, each element written once)
// + weight row sums.
__global__ __launch_bounds__(256) void k_sums(const float* __restrict__ left,
                                              const float* __restrict__ weight,
                                              float* __restrict__ partial,  // [CHUNKS][DIM]
                                              float* __restrict__ rowsum)   // [DIM]
{
    __shared__ float red[4];
    const int b = blockIdx.x;
    const int t = threadIdx.x;

    if (b < LEFT_BLOCKS) {
        // ---- column-sum partial of left ----
        const int cb    = b & 3;     // which 1024-column block
        const int chunk = b >> 2;    // which 64-row chunk
        const int col   = cb * 1024 + t * 4;
        const long base = (long)chunk * CHUNK_ROWS * DIM + col;
        float4 acc = make_float4(0.f, 0.f, 0.f, 0.f);
        #pragma unroll 8
        for (int r = 0; r < CHUNK_ROWS; ++r) {
            const float4 v = *reinterpret_cast<const float4*>(left + base + (long)r * DIM);
            acc.x += v.x; acc.y += v.y; acc.z += v.z; acc.w += v.w;
        }
        *reinterpret_cast<float4*>(partial + (long)chunk * DIM + col) = acc;
    } else {
        // ---- row sums of weight ----
        const int wb   = b - LEFT_BLOCKS;
        const int row0 = wb * ROWS_PER_WBLOCK;
        const int wave = t >> 6, lane = t & 63;
        for (int r = 0; r < ROWS_PER_WBLOCK; ++r) {
            const long base = (long)(row0 + r) * DIM;
            float s = 0.f;
            #pragma unroll
            for (int i = 0; i < 4; ++i) {
                const float4 v =
                    *reinterpret_cast<const float4*>(weight + base + (long)(i * 256 + t) * 4);
                s += v.x + v.y + v.z + v.w;
            }
            #pragma unroll
            for (int off = 32; off > 0; off >>= 1) s += __shfl_down(s, off);
            if (lane == 0) red[wave] = s;
            __syncthreads();
            if (t == 0) rowsum[row0 + r] = red[0] + red[1] + red[2] + red[3];
            __syncthreads();
        }
    }
}

// dot(partial-reduced colsum, rowsum) -> 64 block partials.
// Each thread's grid-stride (16384 = 4*DIM) keeps the column fixed,
// so hoist the rowsum load and multiply once.
__global__ __launch_bounds__(256) void k_dot(const float* __restrict__ partial,
                                             const float* __restrict__ rowsum,
                                             float* __restrict__ bp)
{
    __shared__ float red[4];
    const int idx0 = blockIdx.x * 256 + threadIdx.x;
    const int total = CHUNKS * DIM;          // 524288
    const int stride = 64 * 256;             // 16384, multiple of DIM
    float p = 0.f;
    for (int i = idx0; i < total; i += stride) p += partial[i];
    float s = p * rowsum[idx0 & (DIM - 1)];
    #pragma unroll
    for (int off = 32; off > 0; off >>= 1) s += __shfl_down(s, off);
    const int wave = threadIdx.x >> 6, lane = threadIdx.x & 63;
    if (lane == 0) red[wave] = s;
    __syncthreads();
    if (threadIdx.x == 0) bp[blockIdx.x] = red[0] + red[1] + red[2] + red[3];
}

__global__ void k_final(const float* __restrict__ bp,
                        const float* __restrict__ bias,
                        float* __restrict__ out)
{
    const int t = threadIdx.x;   // 64 threads
    float s = bp[t];
    #pragma unroll
    for (int off = 32; off > 0; off >>= 1) s += __shfl_down(s, off);
    if (t == 0) out[0] = s + bias[0];
}

extern "C" void kernel_launch(void* const* d_in, const int* in_sizes, int n_in,
                              void* d_out, int out_size, void* d_ws, size_t ws_size,
                              hipStream_t stream) {
    const float* left   = (const float*)d_in[0];
    const float* weight = (const float*)d_in[1];
    const float* bias   = (const float*)d_in[2];
    float* out = (float*)d_out;

    // ws layout: partial [128][4096] f32 (2 MB) | rowsum [4096] f32 | bp [64] f32
    float* partial = (float*)d_ws;
    float* rowsum  = partial + (long)CHUNKS * DIM;
    float* bp      = rowsum + DIM;

    k_sums<<<LEFT_BLOCKS + WEIGHT_BLOCKS, 256, 0, stream>>>(left, weight, partial, rowsum);
    k_dot<<<64, 256, 0, stream>>>(partial, rowsum, bp);
    k_final<<<1, 64, 0, stream>>>(bp, bias, out);
}